// Round 1
// baseline (228.601 us; speedup 1.0000x reference)
//
#include <hip/hip_runtime.h>
#include <hip/hip_bf16.h>

#define B_ 512
#define L_ 64
#define H_ 256
#define OUT_ 2048

typedef short bf16x8 __attribute__((ext_vector_type(8)));
typedef float f32x4 __attribute__((ext_vector_type(4)));

__device__ __forceinline__ unsigned short f2bf(float f) {
  union { float f; unsigned int u; } v; v.f = f;
  unsigned int r = (v.u + 0x7FFFu + ((v.u >> 16) & 1u)) >> 16;
  return (unsigned short)r;
}
__device__ __forceinline__ float bf2f(unsigned short s) {
  union { unsigned int u; float f; } v; v.u = ((unsigned int)s) << 16;
  return v.f;
}

// ---------------------------------------------------------------------------
// Kernel 1: Wc (256 x 2048 fp32) -> WcT (2048 x 256 bf16), LDS-tiled transpose
// ---------------------------------------------------------------------------
__global__ __launch_bounds__(256) void wct_kernel(const float* __restrict__ Wc,
                                                  unsigned short* __restrict__ WcT) {
  __shared__ unsigned short tile[64][68];  // pad to dodge bank conflicts
  int bid = blockIdx.x;
  int k0 = (bid & 3) * 64;
  int n0 = (bid >> 2) * 64;
  int tid = threadIdx.x;
#pragma unroll
  for (int j = 0; j < 16; ++j) {
    int idx = tid + j * 256;
    int r = idx >> 6, cc = idx & 63;
    tile[r][cc] = f2bf(Wc[(size_t)(k0 + r) * OUT_ + n0 + cc]);
  }
  __syncthreads();
#pragma unroll
  for (int j = 0; j < 16; ++j) {
    int idx = tid + j * 256;
    int rr = idx >> 6, cc = idx & 63;  // rr = local n, cc = local k
    WcT[(size_t)(n0 + rr) * H_ + k0 + cc] = tile[cc][rr];
  }
}

// ---------------------------------------------------------------------------
// Kernel 2: per-batch recurrence. One 256-thread WG per batch.
// Prologue computes sibling means into zbuf; Wp lives in registers (per-wave
// 64-col slice as MFMA B-fragments, reused across all 63 steps).
// ---------------------------------------------------------------------------
__global__ __launch_bounds__(256, 2) void rec_kernel(
    const float* __restrict__ mol, const int* __restrict__ pidx_g,
    const float* __restrict__ Wp, const float* __restrict__ bp,
    unsigned short* __restrict__ zg) {
  __shared__ unsigned short zbuf[L_ * H_];   // 32768 B, z rows as bf16
  __shared__ float scratch[63 * 128];        // 32256 B, child sums (half of H)
  __shared__ int pidx[L_];                   // 256 B
  __shared__ float cnt[63];                  // 252 B   (total 65532 B)

  int b = blockIdx.x;
  int tid = threadIdx.x;
  int wv = tid >> 6, l = tid & 63, g = l >> 4, c = l & 15;

  if (tid < L_) pidx[tid] = pidx_g[b * L_ + tid];
  if (tid >= 64 && tid < 64 + 63) cnt[tid - 64] = 0.f;
  __syncthreads();
  if (tid >= 1 && tid < 64) atomicAdd(&cnt[pidx[tid]], 1.0f);

  const float* molb = mol + (size_t)b * L_ * H_;
  int hloc = tid & 127, tg = tid >> 7;

  // sibling means -> zbuf (bf16), two h-halves through the 32KB scratch
  for (int hb = 0; hb < 2; ++hb) {
    for (int i = tid; i < 63 * 128; i += 256) scratch[i] = 0.f;
    __syncthreads();
    for (int t = 1 + tg; t < 64; t += 2)
      atomicAdd(&scratch[pidx[t] * 128 + hloc], molb[t * H_ + hb * 128 + hloc]);
    __syncthreads();
    if (tg == 0) zbuf[hb * 128 + hloc] = 0;  // z row 0 = 0
    for (int t = 1 + tg; t < 64; t += 2) {
      int p = pidx[t];
      float ccnt = cnt[p] - 1.0f;
      float own = molb[t * H_ + hb * 128 + hloc];
      float v = (ccnt > 0.f) ? (scratch[p * 128 + hloc] - own) / ccnt : 0.f;
      zbuf[t * H_ + hb * 128 + hloc] = f2bf(v);
    }
    __syncthreads();
  }

  // Load this wave's Wp slice into register B-fragments.
  // k-slot mapping (same for A and B, any consistent permutation is valid):
  //   slot(g,i) -> k = kt*32 + g*8 + i
  bf16x8 bfr[4][8];
#pragma unroll
  for (int nt = 0; nt < 4; ++nt)
#pragma unroll
    for (int kt = 0; kt < 8; ++kt) {
      bf16x8 t8;
#pragma unroll
      for (int i = 0; i < 8; ++i)
        t8[i] = (short)f2bf(Wp[(size_t)(kt * 32 + g * 8 + i) * H_ + wv * 64 + nt * 16 + c]);
      bfr[nt][kt] = t8;
    }
  float bpv[4];
#pragma unroll
  for (int nt = 0; nt < 4; ++nt) bpv[nt] = bp[wv * 64 + nt * 16 + c];
  __syncthreads();

  // 63 sequential steps
  for (int t = 1; t < 64; ++t) {
    int p = pidx[t];
    f32x4 acc0 = {0.f, 0.f, 0.f, 0.f};
    f32x4 acc1 = {0.f, 0.f, 0.f, 0.f};
    f32x4 acc2 = {0.f, 0.f, 0.f, 0.f};
    f32x4 acc3 = {0.f, 0.f, 0.f, 0.f};
#pragma unroll
    for (int kt = 0; kt < 8; ++kt) {
      bf16x8 av = *(const bf16x8*)&zbuf[p * H_ + kt * 32 + g * 8];  // broadcast within 16-lane group
      acc0 = __builtin_amdgcn_mfma_f32_16x16x32_bf16(av, bfr[0][kt], acc0, 0, 0, 0);
      acc1 = __builtin_amdgcn_mfma_f32_16x16x32_bf16(av, bfr[1][kt], acc1, 0, 0, 0);
      acc2 = __builtin_amdgcn_mfma_f32_16x16x32_bf16(av, bfr[2][kt], acc2, 0, 0, 0);
      acc3 = __builtin_amdgcn_mfma_f32_16x16x32_bf16(av, bfr[3][kt], acc3, 0, 0, 0);
    }
    if (l < 16) {  // C row 0 lives in lanes 0-15, reg 0 (all rows equal here)
      int base = t * H_ + wv * 64 + l;
      float v0 = fmaxf(acc0[0] + bpv[0], 0.f) + bf2f(zbuf[base + 0]);
      float v1 = fmaxf(acc1[0] + bpv[1], 0.f) + bf2f(zbuf[base + 16]);
      float v2 = fmaxf(acc2[0] + bpv[2], 0.f) + bf2f(zbuf[base + 32]);
      float v3 = fmaxf(acc3[0] + bpv[3], 0.f) + bf2f(zbuf[base + 48]);
      zbuf[base + 0] = f2bf(v0);
      zbuf[base + 16] = f2bf(v1);
      zbuf[base + 32] = f2bf(v2);
      zbuf[base + 48] = f2bf(v3);
    }
    __syncthreads();
  }

  // dump z (bf16) to global for the logits GEMM
  const unsigned int* zs = (const unsigned int*)zbuf;
  unsigned int* zo = (unsigned int*)(zg + (size_t)b * L_ * H_);
  for (int i = tid; i < L_ * H_ / 2; i += 256) zo[i] = zs[i];
}

// ---------------------------------------------------------------------------
// Kernel 3: logits = z(32768x256 bf16) @ Wc(256x2048) + bc, fp32 out.
// 128x128 tile per WG, 4 waves (2x2), A in XOR-swizzled LDS, B-frags from
// L2-resident WcT directly into registers.
// ---------------------------------------------------------------------------
__global__ __launch_bounds__(256, 2) void gemm_kernel(
    const unsigned short* __restrict__ zg, const unsigned short* __restrict__ WcT,
    const float* __restrict__ bc, float* __restrict__ out) {
  __shared__ unsigned short As[128 * 256];  // 64KB, XOR-swizzled rows
  int bid = blockIdx.x;
  int mb = bid >> 4, nb = bid & 15;  // n-inner: consecutive blocks share A tile
  int tid = threadIdx.x;
  int wv = tid >> 6, l = tid & 63, g = l >> 4, c = l & 15;
  int wm = wv >> 1, wn = wv & 1;

  // stage A tile (coalesced u32 reads, swizzled LDS writes: byte ^= (r&7)<<4)
  const unsigned int* zrow = (const unsigned int*)(zg + (size_t)mb * 128 * H_);
  unsigned int* As32 = (unsigned int*)As;
#pragma unroll
  for (int j = 0; j < 64; ++j) {
    int idx = tid + j * 256;  // 0..16383 u32
    int r = idx >> 7, cu = idx & 127;
    As32[r * 128 + (cu ^ ((r & 7) << 2))] = zrow[idx];
  }

  // B fragments for this wave's 64-col slice (k-slot mapping matches A)
  bf16x8 bfr[4][8];
#pragma unroll
  for (int nt = 0; nt < 4; ++nt) {
    int col = nb * 128 + wn * 64 + nt * 16 + c;
#pragma unroll
    for (int kt = 0; kt < 8; ++kt)
      bfr[nt][kt] = *(const bf16x8*)&WcT[(size_t)col * H_ + kt * 32 + g * 8];
  }
  float bcv[4];
#pragma unroll
  for (int nt = 0; nt < 4; ++nt) bcv[nt] = bc[nb * 128 + wn * 64 + nt * 16 + c];
  __syncthreads();

  f32x4 acc[4][4] = {};
#pragma unroll
  for (int kt = 0; kt < 8; ++kt) {
    bf16x8 a[4];
#pragma unroll
    for (int mt = 0; mt < 4; ++mt) {
      int r = wm * 64 + mt * 16 + c;
      int koff = (kt * 32 + g * 8) ^ ((r & 7) << 3);  // ushort-index swizzle
      a[mt] = *(const bf16x8*)&As[r * 256 + koff];
    }
#pragma unroll
    for (int nt = 0; nt < 4; ++nt)
#pragma unroll
      for (int mt = 0; mt < 4; ++mt)
        acc[mt][nt] = __builtin_amdgcn_mfma_f32_16x16x32_bf16(a[mt], bfr[nt][kt], acc[mt][nt], 0, 0, 0);
  }

  int row0 = mb * 128 + wm * 64;
  int col0 = nb * 128 + wn * 64;
#pragma unroll
  for (int mt = 0; mt < 4; ++mt)
#pragma unroll
    for (int nt = 0; nt < 4; ++nt) {
      int col = col0 + nt * 16 + c;
#pragma unroll
      for (int j = 0; j < 4; ++j) {
        int row = row0 + mt * 16 + g * 4 + j;  // C: row=(l>>4)*4+reg, col=l&15
        out[(size_t)row * OUT_ + col] = acc[mt][nt][j] + bcv[nt];
      }
    }
}

extern "C" void kernel_launch(void* const* d_in, const int* in_sizes, int n_in,
                              void* d_out, int out_size, void* d_ws, size_t ws_size,
                              hipStream_t stream) {
  const float* mol = (const float*)d_in[0];
  const int* pidx = (const int*)d_in[1];
  const float* Wp = (const float*)d_in[2];
  const float* bp = (const float*)d_in[3];
  const float* Wc = (const float*)d_in[4];
  const float* bc = (const float*)d_in[5];
  float* out = (float*)d_out;

  unsigned short* zg = (unsigned short*)d_ws;                 // 32768x256 bf16 = 16MB
  unsigned short* WcT = zg + (size_t)B_ * L_ * H_;            // 2048x256 bf16 = 1MB

  wct_kernel<<<128, 256, 0, stream>>>(Wc, WcT);
  rec_kernel<<<B_, 256, 0, stream>>>(mol, pidx, Wp, bp, zg);
  gemm_kernel<<<(B_ * L_ / 128) * (OUT_ / 128), 256, 0, stream>>>(zg, WcT, bc, out);
}

// Round 2
// 165.041 us; speedup vs baseline: 1.3851x; 1.3851x over previous
//
#include <hip/hip_runtime.h>

#define B_ 512
#define L_ 64
#define H_ 256
#define OUT_ 2048

typedef short bf16x8 __attribute__((ext_vector_type(8)));
typedef float f32x4 __attribute__((ext_vector_type(4)));

static __device__ __forceinline__ unsigned short f2bf(float f) {
  union { float f; unsigned int u; } v; v.f = f;
  unsigned int r = (v.u + 0x7FFFu + ((v.u >> 16) & 1u)) >> 16;
  return (unsigned short)r;
}
static __device__ __forceinline__ float bf2f(unsigned short s) {
  union { unsigned int u; float f; } v; v.u = ((unsigned int)s) << 16;
  return v.f;
}

// ---------------------------------------------------------------------------
// Pack Wc (256x2048 f32) and Wp (256x256 f32) into MFMA-B-fragment-major bf16:
// frag (col16, kt): 64 lanes x 16B contiguous; lane l holds
//   B[k = kt*32 + (l>>4)*8 + i][n = col16*16 + (l&15)], i = 0..7.
// Consumer then does ONE coalesced 16B load per fragment.
// ---------------------------------------------------------------------------
__global__ __launch_bounds__(256) void pack_kernel(
    const float* __restrict__ Wc, const float* __restrict__ Wp,
    unsigned short* __restrict__ WcB, unsigned short* __restrict__ WpB) {
  int bid = blockIdx.x;
  const float* W;
  unsigned short* dst;
  int ncols, col16;
  if (bid < 128) { W = Wc; dst = WcB; ncols = OUT_; col16 = bid; }
  else           { W = Wp; dst = WpB; ncols = H_;   col16 = bid - 128; }
  int tid = threadIdx.x, l = tid & 63, q = tid >> 6;
  int n = col16 * 16 + (l & 15), g = l >> 4;
#pragma unroll
  for (int kk = 0; kk < 2; ++kk) {
    int kt = q + kk * 4;
    bf16x8 v;
#pragma unroll
    for (int i = 0; i < 8; ++i)
      v[i] = (short)f2bf(W[(size_t)(kt * 32 + g * 8 + i) * ncols + n]);
    *(bf16x8*)&dst[(size_t)(col16 * 8 + kt) * 512 + l * 8] = v;
  }
}

// ---------------------------------------------------------------------------
// Fused per-batch kernel: sibling means -> 63-step recurrence (z in LDS as
// swizzled bf16) -> logits GEMM straight out of LDS. One 256-thread WG/batch.
// zbuf swizzle: ushort index ^= (row&7)<<3  (16B-chunk XOR within each row;
// makes both the broadcast rec reads and the 16-row GEMM A-frag gathers
// bank-uniform).
// ---------------------------------------------------------------------------
__global__ __launch_bounds__(256, 2) void fused_kernel(
    const float* __restrict__ mol, const int* __restrict__ pidx_g,
    const float* __restrict__ bp, const unsigned short* __restrict__ WpB,
    const unsigned short* __restrict__ WcB, const float* __restrict__ bc,
    float* __restrict__ out) {
  __shared__ unsigned short zbuf[L_ * H_];  // 32 KB
  __shared__ float scratch[63 * 64];        // 16128 B (child sums, H quarter)
  __shared__ int pidx[L_];
  __shared__ float cnt[63];

  int b = blockIdx.x;
  int tid = threadIdx.x;
  int wv = tid >> 6, l = tid & 63, g = l >> 4, c = l & 15;

  if (tid < L_) pidx[tid] = pidx_g[b * L_ + tid];
  if (tid >= 64 && tid < 127) cnt[tid - 64] = 0.f;
  zbuf[tid] = 0;  // z row 0 = 0 (row 0 swizzle is identity)
  __syncthreads();
  if (tid >= 1 && tid < 64) atomicAdd(&cnt[pidx[tid]], 1.f);

  const float* molb = mol + (size_t)b * L_ * H_;
  int hloc = tid & 63, tg4 = tid >> 6;

  // ---- sibling means -> zbuf (bf16, swizzled), 4 H-quarters ----
  for (int hq = 0; hq < 4; ++hq) {
    for (int i = tid; i < 63 * 64; i += 256) scratch[i] = 0.f;
    __syncthreads();
    for (int t = 1 + tg4; t < 64; t += 4)
      atomicAdd(&scratch[pidx[t] * 64 + hloc], molb[t * H_ + hq * 64 + hloc]);
    __syncthreads();
    for (int t = 1 + tg4; t < 64; t += 4) {
      int p = pidx[t];
      float ccnt = cnt[p] - 1.f;
      float own = molb[t * H_ + hq * 64 + hloc];
      float v = (ccnt > 0.f) ? (scratch[p * 64 + hloc] - own) / ccnt : 0.f;
      int h = hq * 64 + hloc;
      zbuf[(t * H_ + h) ^ ((t & 7) << 3)] = f2bf(v);
    }
    __syncthreads();
  }

  // ---- Wp B-fragments (per-wave 64-col slice) from packed WpB ----
  bf16x8 wfr[4][8];
#pragma unroll
  for (int nt = 0; nt < 4; ++nt)
#pragma unroll
    for (int kt = 0; kt < 8; ++kt)
      wfr[nt][kt] = *(const bf16x8*)&WpB[(size_t)((wv * 4 + nt) * 8 + kt) * 512 + l * 8];
  float bpv[4];
#pragma unroll
  for (int nt = 0; nt < 4; ++nt) bpv[nt] = bp[wv * 64 + nt * 16 + c];

  // ---- 63 sequential recurrence steps ----
  for (int t = 1; t < L_; ++t) {
    int p = pidx[t];
    int sp = (p & 7) << 3;
    f32x4 a0 = {0.f, 0.f, 0.f, 0.f};
    f32x4 a1 = {0.f, 0.f, 0.f, 0.f};
    f32x4 a2 = {0.f, 0.f, 0.f, 0.f};
    f32x4 a3 = {0.f, 0.f, 0.f, 0.f};
#pragma unroll
    for (int kt = 0; kt < 8; ++kt) {
      bf16x8 av = *(const bf16x8*)&zbuf[p * H_ + ((kt * 32 + g * 8) ^ sp)];
      a0 = __builtin_amdgcn_mfma_f32_16x16x32_bf16(av, wfr[0][kt], a0, 0, 0, 0);
      a1 = __builtin_amdgcn_mfma_f32_16x16x32_bf16(av, wfr[1][kt], a1, 0, 0, 0);
      a2 = __builtin_amdgcn_mfma_f32_16x16x32_bf16(av, wfr[2][kt], a2, 0, 0, 0);
      a3 = __builtin_amdgcn_mfma_f32_16x16x32_bf16(av, wfr[3][kt], a3, 0, 0, 0);
    }
    if (l < 16) {  // all C rows equal (broadcast A); use reg 0 of lanes 0-15
      int st = (t & 7) << 3;
      int base = t * H_ + wv * 64 + l;
      int i0 = (base + 0) ^ st, i1 = (base + 16) ^ st;
      int i2 = (base + 32) ^ st, i3 = (base + 48) ^ st;
      float v0 = fmaxf(a0[0] + bpv[0], 0.f) + bf2f(zbuf[i0]);
      float v1 = fmaxf(a1[0] + bpv[1], 0.f) + bf2f(zbuf[i1]);
      float v2 = fmaxf(a2[0] + bpv[2], 0.f) + bf2f(zbuf[i2]);
      float v3 = fmaxf(a3[0] + bpv[3], 0.f) + bf2f(zbuf[i3]);
      zbuf[i0] = f2bf(v0);
      zbuf[i1] = f2bf(v1);
      zbuf[i2] = f2bf(v2);
      zbuf[i3] = f2bf(v3);
    }
    __syncthreads();
  }

  // ---- logits GEMM straight from zbuf: (64 x 256) @ (256 x 2048) ----
  // per wave: 512-col span, 8 chunks of 64 cols
#pragma unroll 1
  for (int nc = 0; nc < 8; ++nc) {
    int colbase = wv * 512 + nc * 64;
    float bcv[4];
#pragma unroll
    for (int nt = 0; nt < 4; ++nt) bcv[nt] = bc[colbase + nt * 16 + c];
    f32x4 acc[4][4] = {};
#pragma unroll
    for (int kh = 0; kh < 2; ++kh) {
      bf16x8 bfr[4][4];
#pragma unroll
      for (int nt = 0; nt < 4; ++nt)
#pragma unroll
        for (int kt = 0; kt < 4; ++kt)
          bfr[nt][kt] = *(const bf16x8*)&WcB[
              (size_t)(((colbase >> 4) + nt) * 8 + kh * 4 + kt) * 512 + l * 8];
#pragma unroll
      for (int kt = 0; kt < 4; ++kt) {
        bf16x8 a[4];
#pragma unroll
        for (int mt = 0; mt < 4; ++mt) {
          int r = mt * 16 + c;
          a[mt] = *(const bf16x8*)&zbuf[
              r * H_ + ((kh * 128 + kt * 32 + g * 8) ^ ((r & 7) << 3))];
        }
#pragma unroll
        for (int nt = 0; nt < 4; ++nt)
#pragma unroll
          for (int mt = 0; mt < 4; ++mt)
            acc[mt][nt] = __builtin_amdgcn_mfma_f32_16x16x32_bf16(
                a[mt], bfr[nt][kt], acc[mt][nt], 0, 0, 0);
      }
    }
#pragma unroll
    for (int mt = 0; mt < 4; ++mt)
#pragma unroll
      for (int nt = 0; nt < 4; ++nt) {
        int col = colbase + nt * 16 + c;
#pragma unroll
        for (int j = 0; j < 4; ++j) {
          int rt = mt * 16 + g * 4 + j;  // C: row=(l>>4)*4+reg, col=l&15
          out[(size_t)(b * 64 + rt) * OUT_ + col] = acc[mt][nt][j] + bcv[nt];
        }
      }
  }
}

extern "C" void kernel_launch(void* const* d_in, const int* in_sizes, int n_in,
                              void* d_out, int out_size, void* d_ws, size_t ws_size,
                              hipStream_t stream) {
  const float* mol = (const float*)d_in[0];
  const int* pidx = (const int*)d_in[1];
  const float* Wp = (const float*)d_in[2];
  const float* bp = (const float*)d_in[3];
  const float* Wc = (const float*)d_in[4];
  const float* bc = (const float*)d_in[5];
  float* out = (float*)d_out;

  unsigned short* WcB = (unsigned short*)d_ws;                  // 1 MB
  unsigned short* WpB = WcB + (size_t)(OUT_ / 16) * 8 * 512;    // 128 KB

  pack_kernel<<<144, 256, 0, stream>>>(Wc, Wp, WcB, WpB);
  fused_kernel<<<B_, 256, 0, stream>>>(mol, pidx, bp, WpB, WcB, bc, out);
}

// Round 4
// 131.786 us; speedup vs baseline: 1.7346x; 1.2523x over previous
//
#include <hip/hip_runtime.h>

#define B_ 512
#define L_ 64
#define H_ 256
#define OUT_ 2048

typedef short bf16x8 __attribute__((ext_vector_type(8)));
typedef float f32x4 __attribute__((ext_vector_type(4)));

static __device__ __forceinline__ unsigned short f2bf(float f) {
  union { float f; unsigned int u; } v; v.f = f;
  unsigned int r = (v.u + 0x7FFFu + ((v.u >> 16) & 1u)) >> 16;
  return (unsigned short)r;
}
static __device__ __forceinline__ float bf2f(unsigned short s) {
  union { unsigned int u; float f; } v; v.u = ((unsigned int)s) << 16;
  return v.f;
}

// ---------------------------------------------------------------------------
// Pack Wc (256x2048 f32) and Wp (256x256 f32) into MFMA-B-fragment-major bf16:
// frag (col16, kt): 64 lanes x 16B; lane l holds
//   B[k = kt*32 + (l>>4)*8 + i][n = col16*16 + (l&15)], i = 0..7.
// ---------------------------------------------------------------------------
__global__ __launch_bounds__(256) void pack_kernel(
    const float* __restrict__ Wc, const float* __restrict__ Wp,
    unsigned short* __restrict__ WcB, unsigned short* __restrict__ WpB) {
  int bid = blockIdx.x;
  const float* W;
  unsigned short* dst;
  int ncols, col16;
  if (bid < 128) { W = Wc; dst = WcB; ncols = OUT_; col16 = bid; }
  else           { W = Wp; dst = WpB; ncols = H_;   col16 = bid - 128; }
  int tid = threadIdx.x, l = tid & 63, q = tid >> 6;
  int n = col16 * 16 + (l & 15), g = l >> 4;
#pragma unroll
  for (int kk = 0; kk < 2; ++kk) {
    int kt = q + kk * 4;
    bf16x8 v;
#pragma unroll
    for (int i = 0; i < 8; ++i)
      v[i] = (short)f2bf(W[(size_t)(kt * 32 + g * 8 + i) * ncols + n]);
    *(bf16x8*)&dst[(size_t)(col16 * 8 + kt) * 512 + l * 8] = v;
  }
}

// ---------------------------------------------------------------------------
// Fused per-batch kernel, level-parallel recurrence.
// Schedule built by wave 0 with LDS-atomic ranking (within-level order is
// irrelevant: same-level nodes are independent). Chunks of <=16 nodes per
// level; one real M=16 MFMA round per chunk.
// zbuf swizzle: ushort index ^= (row&7)<<3.
// ---------------------------------------------------------------------------
__global__ __launch_bounds__(256, 2) void fused_kernel(
    const float* __restrict__ mol, const int* __restrict__ pidx_g,
    const float* __restrict__ bp, const unsigned short* __restrict__ WpB,
    const unsigned short* __restrict__ WcB, const float* __restrict__ bc,
    float* __restrict__ out) {
  __shared__ unsigned short zbuf[65 * H_];  // 33280 B (row 64 = dummy slot)
  __shared__ float scratch[63 * 128];       // 32256 B child sums (H half)
  __shared__ int pidx[L_];
  __shared__ float cnt[64];
  __shared__ int lvlcnt[64];
  __shared__ int lvlbase[64];
  __shared__ int chkbase[64];
  __shared__ int order_s[64];
  __shared__ int cstart_s[64];
  __shared__ int ccnt_s[64];
  __shared__ int nchunks_s;

  int b = blockIdx.x;
  int tid = threadIdx.x;
  int wv = tid >> 6, l = tid & 63, g = l >> 4, c = l & 15;

  if (tid < 64) pidx[tid] = pidx_g[b * L_ + tid];
  if (tid >= 64 && tid < 128) cnt[tid - 64] = 0.f;
  zbuf[tid] = 0;  // z row 0 = 0 (row 0 swizzle is identity)
  __syncthreads();
  if (tid >= 1 && tid < 64) atomicAdd(&cnt[pidx[tid]], 1.f);

  // ---- wave 0: schedule build ----
  if (tid < 64) {
    int t = tid;
    lvlcnt[t] = 0;
    // depth via pointer jumping (6 doublings cover depth <= 64)
    int pp = pidx[t];
    int lev = (t == 0) ? 0 : 1;
#pragma unroll
    for (int it = 0; it < 6; ++it) {
      int dp = __shfl(lev, pp);
      int pp2 = __shfl(pp, pp);
      lev += dp;
      pp = pp2;
    }
    // rank within level by LDS atomic (arrival order; stability not needed)
    int rank = 0;
    if (t >= 1) rank = atomicAdd(&lvlcnt[lev], 1);
    // lane t = accountant for level t (level 0 has lvlcnt 0: root excluded)
    int lc = lvlcnt[t];
    int nchk = (lc + 15) >> 4;
    int offx = lc, chkx = nchk;
#pragma unroll
    for (int d = 1; d < 64; d <<= 1) {
      int u = __shfl_up(offx, d);
      int v2 = __shfl_up(chkx, d);
      if (t >= d) { offx += u; chkx += v2; }
    }
    lvlbase[t] = offx - lc;
    chkbase[t] = chkx - nchk;
    if (t == 63) nchunks_s = chkx;
    if (t >= 1) {
      int pos = lvlbase[lev] + rank;   // same-wave DS ordering: write precedes
      order_s[pos] = t;
      if ((rank & 15) == 0) {
        int cid = chkbase[lev] + (rank >> 4);
        cstart_s[cid] = pos;
        ccnt_s[cid] = min(16, lvlcnt[lev] - rank);
      }
    }
  }

  // ---- sibling means -> zbuf (bf16, swizzled), 2 H-halves ----
  const float* molb = mol + (size_t)b * L_ * H_;
  int hloc = tid & 127, tg2 = tid >> 7;
  for (int hb = 0; hb < 2; ++hb) {
    float mv[32];
#pragma unroll
    for (int k = 0; k < 32; ++k) {
      int t = 1 + tg2 + 2 * k;
      mv[k] = (t < 64) ? molb[t * H_ + hb * 128 + hloc] : 0.f;
    }
    for (int i = tid; i < 63 * 128; i += 256) scratch[i] = 0.f;
    __syncthreads();
#pragma unroll
    for (int k = 0; k < 32; ++k) {
      int t = 1 + tg2 + 2 * k;
      if (t < 64) atomicAdd(&scratch[pidx[t] * 128 + hloc], mv[k]);
    }
    __syncthreads();
#pragma unroll
    for (int k = 0; k < 32; ++k) {
      int t = 1 + tg2 + 2 * k;
      if (t < 64) {
        int p = pidx[t];
        float ccn = cnt[p] - 1.f;
        float v = (ccn > 0.f) ? (scratch[p * 128 + hloc] - mv[k]) / ccn : 0.f;
        zbuf[(t * H_ + hb * 128 + hloc) ^ ((t & 7) << 3)] = f2bf(v);
      }
    }
    __syncthreads();
  }

  // ---- Wp B-fragments (per-wave 64-col slice), step-invariant registers ----
  bf16x8 wfr[4][8];
#pragma unroll
  for (int nt = 0; nt < 4; ++nt)
#pragma unroll
    for (int kt = 0; kt < 8; ++kt)
      wfr[nt][kt] = *(const bf16x8*)&WpB[(size_t)((wv * 4 + nt) * 8 + kt) * 512 + l * 8];
  float bpv[4];
#pragma unroll
  for (int nt = 0; nt < 4; ++nt) bpv[nt] = bp[wv * 64 + nt * 16 + c];
  __syncthreads();

  // ---- level-parallel recurrence: one MFMA round per chunk ----
  int nch = nchunks_s;
  for (int ch = 0; ch < nch; ++ch) {
    int cs = cstart_s[ch], cc = ccnt_s[ch];
    int node = (c < cc) ? order_s[cs + c] : 64;  // A row m = c <- slot m node
    int par = (node < 64) ? pidx[node] : 0;
    int sp = (par & 7) << 3;
    f32x4 a0 = {0.f, 0.f, 0.f, 0.f};
    f32x4 a1 = {0.f, 0.f, 0.f, 0.f};
    f32x4 a2 = {0.f, 0.f, 0.f, 0.f};
    f32x4 a3 = {0.f, 0.f, 0.f, 0.f};
#pragma unroll
    for (int kt = 0; kt < 8; ++kt) {
      bf16x8 av = *(const bf16x8*)&zbuf[par * H_ + ((kt * 32 + g * 8) ^ sp)];
      a0 = __builtin_amdgcn_mfma_f32_16x16x32_bf16(av, wfr[0][kt], a0, 0, 0, 0);
      a1 = __builtin_amdgcn_mfma_f32_16x16x32_bf16(av, wfr[1][kt], a1, 0, 0, 0);
      a2 = __builtin_amdgcn_mfma_f32_16x16x32_bf16(av, wfr[2][kt], a2, 0, 0, 0);
      a3 = __builtin_amdgcn_mfma_f32_16x16x32_bf16(av, wfr[3][kt], a3, 0, 0, 0);
    }
    // epilogue: C row m=(l>>4)*4+j -> node slot m, col=c
#pragma unroll
    for (int j = 0; j < 4; ++j) {
      int m = g * 4 + j;
      int nd = (m < cc) ? order_s[cs + m] : 64;
      int swn = (nd & 7) << 3;
      int base = nd * H_ + wv * 64 + c;
      int i0 = (base + 0) ^ swn, i1 = (base + 16) ^ swn;
      int i2 = (base + 32) ^ swn, i3 = (base + 48) ^ swn;
      float v0 = fmaxf(a0[j] + bpv[0], 0.f) + bf2f(zbuf[i0]);
      float v1 = fmaxf(a1[j] + bpv[1], 0.f) + bf2f(zbuf[i1]);
      float v2 = fmaxf(a2[j] + bpv[2], 0.f) + bf2f(zbuf[i2]);
      float v3 = fmaxf(a3[j] + bpv[3], 0.f) + bf2f(zbuf[i3]);
      zbuf[i0] = f2bf(v0);
      zbuf[i1] = f2bf(v1);
      zbuf[i2] = f2bf(v2);
      zbuf[i3] = f2bf(v3);
    }
    __syncthreads();
  }

  // ---- logits GEMM straight from zbuf: (64 x 256) @ (256 x 2048) ----
#pragma unroll 1
  for (int nc = 0; nc < 8; ++nc) {
    int colbase = wv * 512 + nc * 64;
    float bcv[4];
#pragma unroll
    for (int nt = 0; nt < 4; ++nt) bcv[nt] = bc[colbase + nt * 16 + c];
    f32x4 acc[4][4] = {};
#pragma unroll
    for (int kh = 0; kh < 2; ++kh) {
      bf16x8 bfr[4][4];
#pragma unroll
      for (int nt = 0; nt < 4; ++nt)
#pragma unroll
        for (int kt = 0; kt < 4; ++kt)
          bfr[nt][kt] = *(const bf16x8*)&WcB[
              (size_t)(((colbase >> 4) + nt) * 8 + kh * 4 + kt) * 512 + l * 8];
#pragma unroll
      for (int kt = 0; kt < 4; ++kt) {
        bf16x8 a[4];
#pragma unroll
        for (int mt = 0; mt < 4; ++mt) {
          int r = mt * 16 + c;
          a[mt] = *(const bf16x8*)&zbuf[
              r * H_ + ((kh * 128 + kt * 32 + g * 8) ^ ((r & 7) << 3))];
        }
#pragma unroll
        for (int nt = 0; nt < 4; ++nt)
#pragma unroll
          for (int mt = 0; mt < 4; ++mt)
            acc[mt][nt] = __builtin_amdgcn_mfma_f32_16x16x32_bf16(
                a[mt], bfr[nt][kt], acc[mt][nt], 0, 0, 0);
      }
    }
#pragma unroll
    for (int mt = 0; mt < 4; ++mt)
#pragma unroll
      for (int nt = 0; nt < 4; ++nt) {
        int col = colbase + nt * 16 + c;
#pragma unroll
        for (int j = 0; j < 4; ++j) {
          int rt = mt * 16 + g * 4 + j;  // C: row=(l>>4)*4+reg, col=l&15
          out[(size_t)(b * 64 + rt) * OUT_ + col] = acc[mt][nt][j] + bcv[nt];
        }
      }
  }
}

extern "C" void kernel_launch(void* const* d_in, const int* in_sizes, int n_in,
                              void* d_out, int out_size, void* d_ws, size_t ws_size,
                              hipStream_t stream) {
  const float* mol = (const float*)d_in[0];
  const int* pidx = (const int*)d_in[1];
  const float* Wp = (const float*)d_in[2];
  const float* bp = (const float*)d_in[3];
  const float* Wc = (const float*)d_in[4];
  const float* bc = (const float*)d_in[5];
  float* out = (float*)d_out;

  unsigned short* WcB = (unsigned short*)d_ws;                  // 1 MB
  unsigned short* WpB = WcB + (size_t)(OUT_ / 16) * 8 * 512;    // 128 KB

  pack_kernel<<<144, 256, 0, stream>>>(Wc, Wp, WcB, WpB);
  fused_kernel<<<B_, 256, 0, stream>>>(mol, pidx, bp, WpB, WcB, bc, out);
}